// Round 6
// baseline (441.128 us; speedup 1.0000x reference)
//
#include <hip/hip_runtime.h>
#include <stdint.h>

typedef unsigned short u16;
typedef unsigned int u32;
typedef _Float16 f16;
typedef float v4f __attribute__((ext_vector_type(4)));
typedef f16 v8h __attribute__((ext_vector_type(8)));
typedef f16 v4h __attribute__((ext_vector_type(4)));

#define CC 256
#define NNN 4096

__device__ __forceinline__ u16 f2h(float f) {
  union { f16 h; u16 u; } c; c.h = (f16)f; return c.u;
}
// monotone float<->uint encoding for atomicMax on fp32
__device__ __forceinline__ u32 encf(float f) {
  u32 u = __float_as_uint(f);
  return (u >> 31) ? ~u : (u | 0x80000000u);
}
__device__ __forceinline__ float decf(u32 u) {
  return (u >> 31) ? __uint_as_float(u & 0x7fffffffu) : __uint_as_float(~u);
}
__device__ __forceinline__ void async16(const void* g, void* l) {
  __builtin_amdgcn_global_load_lds(
      (const __attribute__((address_space(1))) uint32_t*)g,
      (__attribute__((address_space(3))) uint32_t*)l, 16, 0, 0);
}

// ---- W [256][256] fp32 -> Ws [256][512] fp16 (hi | lo), K(c)-fast ----
__global__ __launch_bounds__(256) void wsplit(const float* __restrict__ W,
                                              u16* __restrict__ Ws) {
  const int d = blockIdx.x, c = threadIdx.x;
  float w = W[d * 256 + c];
  f16 hi = (f16)w;
  f16 lo = (f16)(w - (float)hi);
  union { f16 h; u16 u; } ch, cl; ch.h = hi; cl.h = lo;
  Ws[d * 512 + c] = ch.u;
  Ws[d * 512 + 256 + c] = cl.u;
}

// ---- per batch: in [C][N] fp32 -> T [N][256] fp16 (transposed, K-fast),
//      and Cb [C][N] fp16 (straight copy) ----
__global__ __launch_bounds__(256) void tsplit(const float* __restrict__ in,
                                              u16* __restrict__ T,
                                              u16* __restrict__ Cb) {
  __shared__ u16 th[64][65];
  const int bb = blockIdx.z;
  const int n0 = blockIdx.x * 64;
  const int c0 = blockIdx.y * 64;
  const int tx = threadIdx.x & 63;
  const int ty = threadIdx.x >> 6;  // 0..3
  const float* ib = in + (size_t)bb * CC * NNN;
  u16* Tb = T + (size_t)bb * NNN * 256;
  u16* Cbb = Cb + (size_t)bb * CC * NNN;
#pragma unroll
  for (int k = 0; k < 16; k++) {
    int r = ty + k * 4;
    float v = ib[(size_t)(c0 + r) * NNN + n0 + tx];
    u16 h = f2h(v);
    th[r][tx] = h;
    Cbb[(size_t)(c0 + r) * NNN + n0 + tx] = h;
  }
  __syncthreads();
#pragma unroll
  for (int k = 0; k < 16; k++) {
    int r = ty + k * 4;
    Tb[(size_t)(n0 + r) * 256 + c0 + tx] = th[tx][r];
  }
}

// ---- TN GEMM over fp16, logical K=512 with per-operand k-masking.
// kA = k0 & ma ; kB = k0 & mb  -> 2-term hi/lo product on one operand.
// BK=64, XOR-swizzled LDS (8-elem chunks, pos = chunk ^ (row&7)).
// Single-buffer (cross-block overlap hides the stage drain).
// MODE 0: out = fp16 hi/lo, pitch 512 (a~).
// MODE 1: out = S fp32 + row/col max atomics; tiles XCD-clustered.
template <int MODE>
__global__ __launch_bounds__(256) void gemm_tn(
    const u16* __restrict__ A, long sAb, int pa, int ma,
    const u16* __restrict__ Bm, long sBb, int pb, int mb, int ktot,
    u16* __restrict__ outb, long sOb, float* __restrict__ S,
    u32* __restrict__ Mru, u32* __restrict__ Mcu) {
  const int bz = blockIdx.z;
  const u16* Ab = A + (size_t)bz * sAb;
  const u16* Bb = Bm + (size_t)bz * sBb;
  int m0, n0;
  if (MODE == 0) {
    m0 = blockIdx.x * 128;
    n0 = blockIdx.y * 128;
  } else {
    const int bidl = blockIdx.x + (int)gridDim.x * blockIdx.y;  // 0..1023
    const int xcd = bidl & 7, idx = bidl >> 3;
    const int mt = (xcd & 3) * 8 + (idx & 7);
    const int nt = (xcd >> 2) * 16 + (idx >> 3);
    m0 = mt * 128;
    n0 = nt * 128;
  }
  const int tid = threadIdx.x;
  const int wave = tid >> 6;
  const int lane = tid & 63;
  const int q = lane >> 4;
  const int l = lane & 15;
  const int l7 = l & 7;
  const int wm = (wave >> 1) * 64;
  const int wn = (wave & 1) * 64;
  const int sr = lane >> 3;  // row-in-group 0..7
  const int sp = lane & 7;   // LDS chunk position 0..7
  const int sg = sp ^ sr;    // global chunk index (swizzle)

  __shared__ alignas(16) u16 sA[128 * 64];
  __shared__ alignas(16) u16 sB[128 * 64];

  v4f zero = {0.f, 0.f, 0.f, 0.f};
  v4f acc[4][4];
#pragma unroll
  for (int i = 0; i < 4; i++)
#pragma unroll
    for (int j = 0; j < 4; j++) acc[i][j] = zero;

  for (int k0 = 0; k0 < ktot; k0 += 64) {
    const int kA = k0 & ma;
    const int kB = k0 & mb;
    __syncthreads();
#pragma unroll
    for (int ii = 0; ii < 4; ii++) {
      int r = wave * 32 + ii * 8 + sr;
      async16(Ab + (size_t)(m0 + r) * pa + kA + sg * 8,
              &sA[r * 64 + sp * 8]);
    }
#pragma unroll
    for (int ii = 0; ii < 4; ii++) {
      int r = wave * 32 + ii * 8 + sr;
      async16(Bb + (size_t)(n0 + r) * pb + kB + sg * 8,
              &sB[r * 64 + sp * 8]);
    }
    __syncthreads();
#pragma unroll
    for (int s = 0; s < 2; s++) {
      const int pa8 = (s * 4 + q) ^ l7;
      v8h af[4], bfr[4];
#pragma unroll
      for (int i = 0; i < 4; i++)
        af[i] = *(const v8h*)&sA[(wm + i * 16 + l) * 64 + pa8 * 8];
#pragma unroll
      for (int j = 0; j < 4; j++)
        bfr[j] = *(const v8h*)&sB[(wn + j * 16 + l) * 64 + pa8 * 8];
#pragma unroll
      for (int i = 0; i < 4; i++)
#pragma unroll
        for (int j = 0; j < 4; j++)
          acc[i][j] = __builtin_amdgcn_mfma_f32_16x16x32_f16(af[i], bfr[j],
                                                             acc[i][j], 0, 0, 0);
    }
  }

  if (MODE == 0) {
    u16* ob = outb + (size_t)bz * sOb;
#pragma unroll
    for (int i = 0; i < 4; i++)
#pragma unroll
      for (int j = 0; j < 4; j++)
#pragma unroll
        for (int r = 0; r < 4; r++) {
          int row = m0 + wm + i * 16 + q * 4 + r;
          int col = n0 + wn + j * 16 + l;
          float v = acc[i][j][r];
          f16 hi = (f16)v;
          f16 lo = (f16)(v - (float)hi);
          union { f16 h; u16 u; } ch, cl; ch.h = hi; cl.h = lo;
          ob[(size_t)row * 512 + col] = ch.u;
          ob[(size_t)row * 512 + 256 + col] = cl.u;
        }
  } else {
#pragma unroll
    for (int i = 0; i < 4; i++)
#pragma unroll
      for (int j = 0; j < 4; j++)
#pragma unroll
        for (int r = 0; r < 4; r++) {
          int row = m0 + wm + i * 16 + q * 4 + r;  // S row n
          int col = n0 + wn + j * 16 + l;          // S col m
          S[(size_t)row * NNN + col] = acc[i][j][r];
        }
    // --- row max (over this block's 128 cols) ---
    float rm[4][4];
#pragma unroll
    for (int i = 0; i < 4; i++)
#pragma unroll
      for (int r = 0; r < 4; r++)
        rm[i][r] = fmaxf(fmaxf(acc[i][0][r], acc[i][1][r]),
                         fmaxf(acc[i][2][r], acc[i][3][r]));
#pragma unroll
    for (int off = 1; off < 16; off <<= 1)
#pragma unroll
      for (int i = 0; i < 4; i++)
#pragma unroll
        for (int r = 0; r < 4; r++)
          rm[i][r] = fmaxf(rm[i][r], __shfl_xor(rm[i][r], off));
    if (l == 0) {
#pragma unroll
      for (int i = 0; i < 4; i++)
#pragma unroll
        for (int r = 0; r < 4; r++)
          atomicMax(&Mru[m0 + wm + i * 16 + q * 4 + r], encf(rm[i][r]));
    }
    // --- col max (over this block's 128 rows) ---
    float cm[4];
#pragma unroll
    for (int j = 0; j < 4; j++) {
      float v = -3e38f;
#pragma unroll
      for (int i = 0; i < 4; i++)
#pragma unroll
        for (int r = 0; r < 4; r++) v = fmaxf(v, acc[i][j][r]);
      cm[j] = v;
    }
#pragma unroll
    for (int off = 16; off < 64; off <<= 1)
#pragma unroll
      for (int j = 0; j < 4; j++) cm[j] = fmaxf(cm[j], __shfl_xor(cm[j], off));
    if (q == 0) {
#pragma unroll
      for (int j = 0; j < 4; j++)
        atomicMax(&Mcu[n0 + wn + j * 16 + l], encf(cm[j]));
    }
  }
}

// ---- FUSED full-K PV: block = 512 threads (8 waves), owns all 256 c-rows
// x a 32-wide x-strip, k loops over the FULL 4096 -> L computed in-block,
// output divided and written directly (no Ppart, no pv_reduce).
// Inner step structure identical to the proven pv_part loop:
// async16 V->sA[256x64], S read + exp + swizzled pack -> sB[32x64],
// 2 barriers, MFMA. Per wave: 64c x 16x tile, acc[4], 8 MFMA/step.
// Grid (2-batch launch): 128 strips x 2 which x 2 bp = 512 blocks
// (2 blocks/CU, 4 waves/SIMD); (which,bp) constant per XCD -> each XCD's
// L2 holds one 2 MB V slab.
__global__ __launch_bounds__(512) void pv_full(
    const u16* __restrict__ aV, const u16* __restrict__ bV,
    const float* __restrict__ S, const u32* __restrict__ Mru,
    const u32* __restrict__ Mcu, float* __restrict__ outA,
    float* __restrict__ outB, int batch) {
  const int lin = blockIdx.x + 128 * (blockIdx.y + 2 * blockIdx.z);  // 0..511
  const int xcd = lin & 7;
  const int which = xcd & 1;
  const int bp = (xcd >> 1) & 1;
  const int strip = (lin >> 3) + ((xcd >> 2) & 1) * 64;  // 0..127
  const int x0 = strip * 32;
  const u16* Av = (which ? bV : aV) + (size_t)(batch + bp) * (CC * NNN);
  const u32* Mst = (which ? Mru : Mcu) + bp * 4096;
  const float* Sg = S + (size_t)bp * ((size_t)NNN * NNN);
  float* Outp = (which ? outB : outA) + (size_t)(batch + bp) * CC * NNN;

  const int tid = threadIdx.x;
  const int wave = tid >> 6, lane = tid & 63, q = lane >> 4, l = lane & 15;
  const int l7 = l & 7;
  const int wc = (wave >> 1) * 64;   // wave's c-base (4 groups of 64)
  const int wx = (wave & 1) * 16;    // wave's x-half within the 32-strip
  // V staging coords: thread stages 4 16B chunks; per wave each ii covers
  // 8 contiguous rows (LDS dest = wave-uniform base + lane*16).
  const int rb = tid >> 3;           // 0..63
  const int spv = tid & 7;
  // S coords: thread owns x=xr and a 4-wide k slice at kb.
  // which=1 (x=n rows of S): xr = tid>>4 (0..31), kb=(tid&15)*4, float4 read
  // which=0 (x=m cols of S): xr = tid&31, kb=(tid>>5)*4, 4 strided reads
  const int xr = which ? (tid >> 4) : (tid & 31);
  const int kb = which ? ((tid & 15) * 4) : ((tid >> 5) * 4);

  __shared__ alignas(16) u16 sA[256 * 64];  // V tile 32 KB
  __shared__ alignas(16) u16 sB[32 * 64];   // P tile 4 KB
  __shared__ float lshf[512];
  __shared__ float Lx[32];

  v4f zero = {0.f, 0.f, 0.f, 0.f};
  v4f acc[4];
#pragma unroll
  for (int i = 0; i < 4; i++) acc[i] = zero;

  const float mx = decf(Mst[x0 + xr]);
  float lsum = 0.f;

  for (int k0 = 0; k0 < NNN; k0 += 64) {
    __syncthreads();
    // stage V: 256 rows x 64 k fp16, XOR-swizzled chunks
#pragma unroll
    for (int ii = 0; ii < 4; ii++) {
      int r = ii * 64 + rb;
      int sg = spv ^ (r & 7);
      async16(Av + (size_t)r * NNN + k0 + sg * 8, &sA[r * 64 + spv * 8]);
    }
    // S read + exp + pack (4 elements/thread)
    float e[4];
    if (which) {
      float4 v = *(const float4*)(Sg + (size_t)(x0 + xr) * NNN + k0 + kb);
      e[0] = __expf(v.x - mx);
      e[1] = __expf(v.y - mx);
      e[2] = __expf(v.z - mx);
      e[3] = __expf(v.w - mx);
    } else {
      const float* gp = Sg + (size_t)(k0 + kb) * NNN + x0 + xr;
#pragma unroll
      for (int j = 0; j < 4; j++) e[j] = __expf(gp[(size_t)j * NNN] - mx);
    }
    lsum += (e[0] + e[1]) + (e[2] + e[3]);
    v4h pk;
#pragma unroll
    for (int j = 0; j < 4; j++) pk[j] = (f16)e[j];
    // P[x=xr][k=kb..kb+3] -> sB row xr, chunk g=kb>>3 (swizzled), half (kb&4)
    *(v4h*)&sB[xr * 64 + ((kb >> 3) ^ (xr & 7)) * 8 + (kb & 4)] = pk;
    __syncthreads();
    // MFMA: per wave 64c x 16x, K=64
#pragma unroll
    for (int s = 0; s < 2; s++) {
      const int pa8 = (s * 4 + q) ^ l7;
      v8h af[4], bfr;
#pragma unroll
      for (int i = 0; i < 4; i++)
        af[i] = *(const v8h*)&sA[(wc + i * 16 + l) * 64 + pa8 * 8];
      bfr = *(const v8h*)&sB[(wx + l) * 64 + pa8 * 8];
#pragma unroll
      for (int i = 0; i < 4; i++)
        acc[i] = __builtin_amdgcn_mfma_f32_16x16x32_f16(af[i], bfr,
                                                        acc[i], 0, 0, 0);
    }
  }

  // L reduction: sum the 16 per-thread partials of each x, then invert
  __syncthreads();
  lshf[tid] = lsum;
  __syncthreads();
  if (tid < 32) {
    float s = 0.f;
#pragma unroll
    for (int c = 0; c < 16; c++)
      s += which ? lshf[tid * 16 + c] : lshf[c * 32 + tid];
    Lx[tid] = 1.0f / s;
  }
  __syncthreads();

  const float rl = Lx[wx + l];
#pragma unroll
  for (int i = 0; i < 4; i++)
#pragma unroll
    for (int r = 0; r < 4; r++) {
      int c = wc + i * 16 + q * 4 + r;
      Outp[(size_t)c * NNN + x0 + wx + l] = acc[i][r] * rl;
    }
}

extern "C" void kernel_launch(void* const* d_in, const int* in_sizes, int n_in,
                              void* d_out, int out_size, void* d_ws,
                              size_t ws_size, hipStream_t stream) {
  const float* a = (const float*)d_in[0];
  const float* b = (const float*)d_in[1];
  const float* W = (const float*)d_in[2];
  float* out = (float*)d_out;

  char* ws = (char*)d_ws;
  u16* Ws = (u16*)(ws);                     // 262144
  u16* aT = (u16*)(ws + 262144);            // 4*4096*256*2 = 8388608
  u16* bT = (u16*)(ws + 8650752);           // 8388608
  u16* aCb = (u16*)(ws + 17039360);         // 8388608
  u16* bCb = (u16*)(ws + 25427968);         // 8388608
  u16* ats = (u16*)(ws + 33816576);         // 4*4096*512*2 = 16777216
  u32* Mru = (u32*)(ws + 50593792);         // [4][4096] u32 = 65536
  u32* Mcu = (u32*)(ws + 50659328);         // 65536
  float* Sbuf = (float*)(ws + 50724864);    // 2 batches * 64 MB = 134217728
                                            // ends ~184.9 MB

  wsplit<<<dim3(256), 256, 0, stream>>>(W, Ws);
  tsplit<<<dim3(64, 4, 4), 256, 0, stream>>>(a, aT, aCb);
  tsplit<<<dim3(64, 4, 4), 256, 0, stream>>>(b, bT, bCb);
  // a~[n][d] = sum_c aT[n][c] * (Whi+Wlo)[d][c], K=512, out fp16 hi|lo
  gemm_tn<0><<<dim3(32, 2, 4), 256, 0, stream>>>(
      aT, (long)NNN * 256, 256, 255, Ws, 0, 512, 511, 512,
      ats, (long)NNN * 512, nullptr, nullptr, nullptr);
  hipMemsetAsync(Mru, 0, 131072, stream);  // all 4 batches' Mru+Mcu

  for (int p = 0; p < 4; p += 2) {
    // S for batch p and p+1 into the two Sbuf slabs
    for (int h = 0; h < 2; h++) {
      const u16* atp = ats + (size_t)(p + h) * NNN * 512;
      const u16* btp = bT + (size_t)(p + h) * NNN * 256;
      gemm_tn<1><<<dim3(32, 32, 1), 256, 0, stream>>>(
          atp, 0, 512, 511, btp, 0, 256, 255, 512,
          nullptr, 0, Sbuf + (size_t)h * NNN * NNN,
          Mru + (p + h) * 4096, Mcu + (p + h) * 4096);
    }
    pv_full<<<dim3(128, 2, 2), 512, 0, stream>>>(
        aCb, bCb, Sbuf, Mru + p * 4096, Mcu + p * 4096,
        out, out + 4194304, p);
  }
}